// Round 6
// baseline (88.242 us; speedup 1.0000x reference)
//
#include <hip/hip_runtime.h>

// S4D kernel: K[h,l] = 2 * Re( sum_n Ct[h,n] * z[h,n]^l )
//   z  = exp(dtA),  dtA = (-exp(log_A_real) + i*A_imag) * exp(log_dt[h])
//   Ct = (C_real + i*C_imag) * (z - 1) / A
//
// R6 structure: 512-thread blocks (one per h), t = tid & 255, slice = tid>>8.
//  - n-SPLIT ACROSS SLICES: slice s handles n in [16s, 16s+16) for all 16 j.
//    Doubles resident waves (4 blocks/CU x 8 waves = 32 waves/CU, HW max)
//    without duplicating the LDS factor tables (the j-split alternative
//    would double LDS bytes).
//  - SCALAR recurrence (not packed): v_pk_* on CDNA4 costs the same cycles
//    as 2 scalar ops (157 TF = scalar rate); scalar halves acc registers
//    (acc[16] floats) -> fits <=64 VGPR -> 8 waves/EU.
//  - LDS factor tables (no per-(t,n) transcendentals):
//      T0[n][t&15] = z^(t&15);  U1[n][t>>4] = {Ct z^(16m), Ct z^(16m+256)}
//    x0 = Re(U1.lo*T0) = Re(Ct z^t), x1 = Re(U1.hi*T0) = Re(Ct z^(t+256)).
//  - real 2nd-order recurrence x_{j+1} = 2Re(w) x_j - |w|^2 x_{j-1}, w=z^256,
//    ping-pong (2 ops + 1 acc add per (n,j)).
//  - block-uniform adaptive j-cutoff + per-thread decay skip (TOL=1e-3 vs
//    3.9e-2 threshold).
//  - cross-slice reduction via 16 KB LDS buffer; coalesced stores.

#define N2    32
#define LLEN  4096
#define BLK   512
#define TQ    256           // t range
#define CL    16            // j per t
#define TOL   1e-3f

typedef float v2f __attribute__((ext_vector_type(2)));

__global__ __launch_bounds__(BLK, 8) void s4d_kernel(
    const float* __restrict__ log_dt,
    const float* __restrict__ C_real,
    const float* __restrict__ C_imag,
    const float* __restrict__ log_A_real,
    const float* __restrict__ A_imag,
    float* __restrict__ out)
{
    const int h   = blockIdx.x;
    const int tid = threadIdx.x;
    const int t   = tid & (TQ - 1);
    const int sl  = tid >> 8;          // n-slice: 0 or 1

    __shared__ v2f    sT0[N2][16];     // z^k
    __shared__ float4 sU1[N2][16];     // {Ct z^(16m)}, {Ct z^(16m+256)}
    __shared__ v2f    sAB[N2];         // {2Re(w), -|w|^2}
    __shared__ v2f    sCt[N2];
    __shared__ float  sDrl2[N2];       // Re(dtA)*log2(e)
    __shared__ double sTrev[N2];       // step phase (revolutions), double
    __shared__ float  sRed[CL][TQ];    // cross-slice reduction buffer (16 KB)
    __shared__ float  sS, sRmax, sDrmax;
    __shared__ int    sJcut;

    // ---- stage A: per-(h,n) params, lanes 0..31 (wave 0, cold) ----
    if (tid < N2) {
        const int n = tid;
        const float dt = __expf(log_dt[h]);
        const float aR = -__expf(log_A_real[h * N2 + n]);
        const float aI = A_imag[h * N2 + n];
        const float dR = aR * dt;

        const double trev = (double)aI * (double)dt * 0.15915494309189535;

        // z = exp(dtA)
        double pz = trev; pz -= floor(pz);
        const float e1 = __expf(dR);
        const float zr = e1 * __builtin_amdgcn_cosf((float)pz);
        const float zi = e1 * __builtin_amdgcn_sinf((float)pz);

        // q = (z-1)/A ; Ct = C*q
        const float inv = 1.0f / (aR * aR + aI * aI);
        const float nr  = zr - 1.0f;
        const float qr  = (nr * aR + zi * aI) * inv;
        const float qi  = (zi * aR - nr * aI) * inv;
        const float c_r = C_real[h * N2 + n], c_i = C_imag[h * N2 + n];
        const float Ctr = c_r * qr - c_i * qi;
        const float Cti = c_r * qi + c_i * qr;

        // w = z^256
        double p256 = trev * 256.0; p256 -= floor(p256);
        const float ew = __expf(dR * 256.0f);
        const float wx = ew * __builtin_amdgcn_cosf((float)p256);
        const float r2 = ew * ew;
        const float drl2 = dR * 1.4426950408889634f;

        sCt[n]   = (v2f){Ctr, Cti};
        sDrl2[n] = drl2;
        sTrev[n] = trev;
        sAB[n]   = (v2f){2.0f * wx, -r2};

        // block bounds: S >= sum|Ct|, rmax = max|w|, drmax = max drl2
        float S = fabsf(Ctr) + fabsf(Cti);
        float r = ew;
        float dm = drl2;
#pragma unroll
        for (int m = 16; m >= 1; m >>= 1) {
            S  += __shfl_xor(S, m, 32);
            r   = fmaxf(r,  __shfl_xor(r,  m, 32));
            dm  = fmaxf(dm, __shfl_xor(dm, m, 32));
        }
        if (n == 0) {
            sS = S; sRmax = r; sDrmax = dm;
            int jc = CL;
            if (r < 0.9999f) {
                const float tail0 = 2.0f * S / (1.0f - r);
                jc = 0;
                float rj = 1.0f;
                while (jc < CL && tail0 * rj >= TOL) { rj *= r; ++jc; }
            }
            sJcut = jc;
        }
    }
    __syncthreads();

    // ---- stage B: factor tables, 1024 tasks / 512 threads ----
#pragma unroll
    for (int it = 0; it < 2; ++it) {
        const int tau = tid + BLK * it;
        if (tau < 512) {                       // T0 (it==0: uniform branch)
            const int n = tau >> 4, k = tau & 15;
            double p = sTrev[n] * (double)k; p -= floor(p);
            const float g = __builtin_amdgcn_exp2f(sDrl2[n] * (float)k);
            sT0[n][k] = (v2f){ g * __builtin_amdgcn_cosf((float)p),
                               g * __builtin_amdgcn_sinf((float)p) };
        } else {                               // U1 (it==1)
            const int tu = tau - 512;
            const int n = tu >> 4, m = tu & 15;
            const v2f    Ct = sCt[n];
            const double tr = sTrev[n];
            const float  dl = sDrl2[n];

            double p0 = tr * (double)(16 * m); p0 -= floor(p0);
            const float g0 = __builtin_amdgcn_exp2f(dl * (float)(16 * m));
            const float c0 = g0 * __builtin_amdgcn_cosf((float)p0);
            const float s0 = g0 * __builtin_amdgcn_sinf((float)p0);

            double p1 = tr * (double)(16 * m + 256); p1 -= floor(p1);
            const float g1 = __builtin_amdgcn_exp2f(dl * (float)(16 * m + 256));
            const float c1 = g1 * __builtin_amdgcn_cosf((float)p1);
            const float s1 = g1 * __builtin_amdgcn_sinf((float)p1);

            sU1[n][m] = make_float4(Ct.x * c0 - Ct.y * s0,
                                    Ct.x * s0 + Ct.y * c0,
                                    Ct.x * c1 - Ct.y * s1,
                                    Ct.x * s1 + Ct.y * c1);
        }
    }
    __syncthreads();

    float acc[CL];
#pragma unroll
    for (int j = 0; j < CL; ++j) acc[j] = 0.0f;

    const int jcut = __builtin_amdgcn_readfirstlane(sJcut);
    bool active = (jcut > 0);
    {
        const float rmax = sRmax;
        if (rmax < 0.9999f) {
            const float bound = 2.0f * sS *
                __builtin_amdgcn_exp2f(sDrmax * (float)t) / (1.0f - rmax);
            if (bound < TOL) active = false;
        }
    }

    if (active) {
        const int t0 = t & 15, t1 = t >> 4;
        const int nbase = sl * 16;

        for (int ch = 0; ch < 2; ++ch) {
            const int nb = nbase + ch * 8;
            float xa[8], xb[8], ca[8], cb[8];

#pragma unroll
            for (int k = 0; k < 8; ++k) {
                const int n = nb + k;
                const v2f    b = sT0[n][t0];        // ds_read_b64
                const float4 u = sU1[n][t1];        // ds_read_b128 (broadcast)
                xa[k] = __builtin_fmaf(-u.y, b.y, u.x * b.x);  // Re(Ct z^t)
                xb[k] = __builtin_fmaf(-u.w, b.y, u.z * b.x);  // Re(Ct z^(t+256))
                const v2f ab = sAB[n];              // ds_read_b64
                ca[k] = ab.x;  cb[k] = ab.y;
            }

            // j = 0, 1
#pragma unroll
            for (int k = 0; k < 8; ++k) acc[0] += xa[k];
            if (jcut > 1) {
#pragma unroll
                for (int k = 0; k < 8; ++k) acc[1] += xb[k];
            }

            // j = 2..15: scalar ping-pong (mul+fma+add per (n,j), no copies)
#pragma unroll
            for (int jp = 0; jp < (CL - 2) / 2; ++jp) {
                const int j = 2 + 2 * jp;
                if (j < jcut) {
#pragma unroll
                    for (int k = 0; k < 8; ++k) {
                        xa[k] = ca[k] * xb[k] + cb[k] * xa[k];   // x_j
                        acc[j] += xa[k];
                    }
#pragma unroll
                    for (int k = 0; k < 8; ++k) {
                        xb[k] = ca[k] * xa[k] + cb[k] * xb[k];   // x_{j+1}
                        acc[j + 1] += xb[k];
                    }
                }
            }
        }
    }

    // ---- cross-slice reduction ----
    if (sl == 0) {
#pragma unroll
        for (int j = 0; j < CL; ++j) sRed[j][t] = acc[j];
    }
    __syncthreads();
    if (sl == 1) {
#pragma unroll
        for (int j = 0; j < CL; ++j) sRed[j][t] += acc[j];
    }
    __syncthreads();

    // ---- store: thread (t, sl) writes j in [8*sl, 8*sl+8), coalesced ----
    float* __restrict__ o = out + (size_t)h * LLEN + sl * (8 * TQ) + t;
#pragma unroll
    for (int jj = 0; jj < 8; ++jj)
        o[jj * TQ] = 2.0f * sRed[8 * sl + jj][t];
}

extern "C" void kernel_launch(void* const* d_in, const int* in_sizes, int n_in,
                              void* d_out, int out_size, void* d_ws, size_t ws_size,
                              hipStream_t stream) {
    const float* log_dt     = (const float*)d_in[0];
    const float* C_real     = (const float*)d_in[1];
    const float* C_imag     = (const float*)d_in[2];
    const float* log_A_real = (const float*)d_in[3];
    const float* A_imag     = (const float*)d_in[4];
    float* out = (float*)d_out;

    const int H = in_sizes[0];  // 1024; one block per h
    s4d_kernel<<<dim3(H), dim3(BLK), 0, stream>>>(
        log_dt, C_real, C_imag, log_A_real, A_imag, out);
}